// Round 14
// baseline (149.256 us; speedup 1.0000x reference)
//
#include <hip/hip_runtime.h>
#include <hip/hip_bf16.h>

// Problem constants: B=64, Cin=3, H=W=64, O=16, k=7, fh=fw=58
#define NBUCK 2048
#define WB 0.005859375f         // bucket width = 12/2048, range [-6, 6)
#define SCALE 170.6666667f      // 1/WB

// output geometry
#define SEG 10092u              // fh*fh*Cin
#define OSEG 161472u            // O*SEG
#define OUT1 10334208u          // B*OSEG
#define NOUT 31002624u          // 3*OUT1

// scratch in the TAIL of d_out (fill overwrites it last). float offsets:
// table slots per channel: [0..16)=F-parts(4 planes each), [16..28)=rows, [28..40)=cols
#define TAIL_BASE (NOUT - 524288u)     // 30,478,336
#define P_TTAB 0u                       // [120][2049] T tables = 245,880
#define P_STAB 245880u                  // [120] S per table
#define P_PACK 246000u                  // [3][144][64] exact corner pixels = 27,648

typedef float v4f __attribute__((ext_vector_type(4)));

// ---------------------------------------------------------------------------
// DIAGNOSTIC ROUND (R14): graph = build,build,query(dummy),build,query(real),
// fill. Distinguishes "~70us harness-fill floor" (total stays ~72-76) from
// "build/query hide ~51us" (total >= 126; value solves (b,q) via 3b+2q).
// All kernels identical to R13; build is idempotent; the last build re-zeros
// the real gsum bank before the real query accumulates into it.
// ---------------------------------------------------------------------------

__global__ __launch_bounds__(1024) void build_kernel(
    const float* __restrict__ x, float* __restrict__ tail, float* __restrict__ gsum)
{
    __shared__ float sH[NBUCK];         // 8 KB
    const int blk = blockIdx.x;         // == table index, 0..119
    const int c   = blk / 40;
    const int t40 = blk - c * 40;
    for (int i = threadIdx.x; i < NBUCK; i += 1024) sH[i] = 0.f;
    if (blk == 0 && threadIdx.x < 64) gsum[threadIdx.x] = 0.f;
    __syncthreads();

    if (t40 < 16) {
        // F-part: planes 4g..4g+3 of channel c (+ corner pack)
        const int g = t40;
        for (int pb = 0; pb < 4; ++pb) {
            const int batch = g * 4 + pb;
            const int plane = batch * 3 + c;
            float4 val = ((const float4*)x)[plane * 1024 + threadIdx.x];
            float vv[4] = {val.x, val.y, val.z, val.w};
            const int pix0 = threadIdx.x * 4;
#pragma unroll
            for (int e = 0; e < 4; ++e) {
                const int idx = pix0 + e;
                const int py = idx >> 6, px = idx & 63;
                const float v = vv[e];
                const int b = min(max((int)fmaf(v, SCALE, 1024.f), 0), NBUCK - 1);
                atomicAdd(&sH[b], 1.f);
                const bool rb = (py < 6) | (py >= 58);
                const bool cb = (px < 6) | (px >= 58);
                if (rb & cb) {
                    const int ri = (py < 6) ? py : py - 52;
                    const int ci = (px < 6) ? px : px - 52;
                    tail[P_PACK + ((unsigned)c * 144 + ri * 12 + ci) * 64u + batch] = v;
                }
            }
        }
    } else if (t40 < 28) {
        // row table ri: row py over all 64 planes of channel c (4096 px)
        const int ri = t40 - 16;
        const int py = (ri < 6) ? ri : ri + 52;
        const int b_ = threadIdx.x >> 4, q = threadIdx.x & 15;
        float4 val = ((const float4*)x)[(b_ * 3 + c) * 1024 + py * 16 + q];
        float vv[4] = {val.x, val.y, val.z, val.w};
#pragma unroll
        for (int e = 0; e < 4; ++e) {
            const int b = min(max((int)fmaf(vv[e], SCALE, 1024.f), 0), NBUCK - 1);
            atomicAdd(&sH[b], 1.f);
        }
    } else {
        // col table ci: column px over all rows/planes of channel c (4096 px)
        const int ci = t40 - 28;
        const int px = (ci < 6) ? ci : ci + 52;
        const int b_ = threadIdx.x >> 4, py0 = (threadIdx.x & 15) * 4;
        const float* base = x + (b_ * 3 + c) * 4096 + px;
#pragma unroll
        for (int e = 0; e < 4; ++e) {
            const float v = base[(py0 + e) * 64];
            const int b = min(max((int)fmaf(v, SCALE, 1024.f), 0), NBUCK - 1);
            atomicAdd(&sH[b], 1.f);
        }
    }
    __syncthreads();

    // wave 0: double prefix scan entirely in LDS/registers
    if (threadIdx.x < 64) {
        const int lane = threadIdx.x;
        float carry = 0.f, t0acc = 0.f;
        for (int ch = 0; ch < 32; ++ch) {
            const int b = ch * 64 + lane;
            const float cnt = sH[b];
            t0acc += (float)b * cnt;
            float ic = cnt;
#pragma unroll
            for (int off = 1; off < 64; off <<= 1) {
                const float t = __shfl_up(ic, off);
                if (lane >= off) ic += t;
            }
            sH[b] = carry + ic;             // inclusive prefix P (in place)
            carry += __shfl(ic, 63);
        }
        const float N = carry;
#pragma unroll
        for (int off = 32; off > 0; off >>= 1) t0acc += __shfl_down(t0acc, off);
        const float t0tot = __shfl(t0acc, 0);
        const float T0 = WB * (t0tot + 0.5f * N);

        float* T = tail + P_TTAB + (unsigned)blk * 2049u;
        float carryQ = 0.f;
        for (int ch = 0; ch < 32; ++ch) {
            const int b = ch * 64 + lane;
            const float pv = sH[b];
            float ic = pv;
#pragma unroll
            for (int off = 1; off < 64; off <<= 1) {
                const float t = __shfl_up(ic, off);
                if (lane >= off) ic += t;
            }
            const float Q = carryQ + ic - pv;   // exclusive prefix of P
            T[b] = T0 + WB * (2.f * Q - (float)b * N);
            carryQ += __shfl(ic, 63);
        }
        if (lane == 0) {
            T[NBUCK] = T0 + WB * (2.f * carryQ - (float)NBUCK * N);
            tail[P_STAB + blk] = T0 - 6.f * N;  // sum of snapped values
        }
    }
}

__global__ __launch_bounds__(256) void query_kernel(
    const float* __restrict__ Kh, const float* __restrict__ Km,
    const float* __restrict__ tail, float* __restrict__ gsum)
{
    __shared__ float sC[2304];
    __shared__ float sredA[32][8];
    __shared__ float sredL[32][8];

    const int c  = blockIdx.x / 49;
    const int t  = blockIdx.x - c * 49;
    const int dy = t / 7, dx = t - dy * 7;

    for (int i = threadIdx.x; i < 2304; i += 256) {
        const int cell = i >> 6, batch = i & 63;
        const int qr = cell / 6, qc = cell - qr * 6;
        const int ri = (qr < dy) ? qr : 6 + qr;
        const int ci = (qc < dx) ? qc : 6 + qc;
        sC[i] = tail[P_PACK + ((unsigned)c * 144 + ri * 12 + ci) * 64u + batch];
    }
    __syncthreads();

    const int q  = threadIdx.x >> 3;    // 0..31 = hm*16+o
    const int sl = threadIdx.x & 7;
    const int hm = q >> 4, o = q & 15;
    const float k = (hm ? Km : Kh)[o * 147 + c * 49 + t];

    float accA = 0.f, accL = 0.f;
    for (int step = 0; step < 288; ++step) {          // exact corners
        const float v = sC[sl + 8 * step];
        accA += fabsf(k - v);
        accL += k - v;
    }
    if (sl == 0) {
        const float u = fmaf(k, SCALE, 1024.f);
        const int j = min(max((int)u, 0), NBUCK - 1);
        const float fr = u - (float)j;
        float A = 0.f, Sm = 0.f;
#pragma unroll
        for (int s = 0; s < 28; ++s) {
            int slot; float sgn;
            if (s < 16)      { slot = s; sgn = 1.f; }
            else if (s < 22) { const int qq = s - 16; slot = 16 + ((qq < dy) ? qq : 6 + qq); sgn = -1.f; }
            else             { const int qq = s - 22; slot = 28 + ((qq < dx) ? qq : 6 + qq); sgn = -1.f; }
            const float* T = tail + P_TTAB + (unsigned)(c * 40 + slot) * 2049u;
            const float lerp = T[j] + fr * (T[j + 1] - T[j]);
            A  += sgn * lerp;
            Sm += sgn * tail[P_STAB + c * 40 + slot];
        }
        accA += A;
        accL += k * 212992.f - Sm;      // 212992 = (58*58 - 36) * 64
    }
    sredA[q][sl] = accA;
    sredL[q][sl] = accL;
    __syncthreads();
    if (threadIdx.x < 64) {
        const int idx  = threadIdx.x >> 1;
        const int part = threadIdx.x & 1;
        const float (*sr)[8] = part ? sredL : sredA;
        float s = 0.f;
#pragma unroll
        for (int qq = 0; qq < 8; ++qq) s += sr[idx][qq];
        atomicAdd(&gsum[part * 32 + idx], s);
    }
}

__global__ __launch_bounds__(256) void fill_kernel(
    const float* __restrict__ gsum, v4f* __restrict__ out, unsigned n4)
{
    __shared__ float sv[48];
    if (threadIdx.x < 48) {
        const int o = threadIdx.x & 15, grp = threadIdx.x >> 4;
        const float h = -0.5f * (gsum[32 + o] + gsum[o]);
        const float m =  0.5f * (gsum[16 + o] - gsum[48 + o]);
        sv[threadIdx.x] = (grp == 0) ? (h - m) : ((grp == 1) ? h : m);
    }
    __syncthreads();
    const unsigned stride = gridDim.x * blockDim.x;
    for (unsigned i = blockIdx.x * blockDim.x + threadIdx.x; i < n4; i += stride) {
        const unsigned f = i * 4u;
        const unsigned w   = f / OUT1;
        const unsigned rem = f - w * OUT1;
        const unsigned o   = (rem % OSEG) / SEG;
        const float val = sv[w * 16 + o];
        v4f pk = {val, val, val, val};
        __builtin_nontemporal_store(pk, &out[i]);
    }
}

extern "C" void kernel_launch(void* const* d_in, const int* in_sizes, int n_in,
                              void* d_out, int out_size, void* d_ws, size_t ws_size,
                              hipStream_t stream)
{
    const float* x  = (const float*)d_in[0];
    const float* Kh = (const float*)d_in[1];
    const float* Km = (const float*)d_in[2];
    float* out   = (float*)d_out;
    float* tail  = out + TAIL_BASE;
    float* gsum  = (float*)d_ws;        // real bank: 64 floats
    float* gdump = gsum + 64;           // dummy bank for the extra query

    // --- diagnostic replication: 3x build, 2x query (one dummy) ---
    build_kernel<<<120, 1024, 0, stream>>>(x, tail, gsum);
    build_kernel<<<120, 1024, 0, stream>>>(x, tail, gsum);
    query_kernel<<<147, 256, 0, stream>>>(Kh, Km, tail, gdump);   // dummy
    build_kernel<<<120, 1024, 0, stream>>>(x, tail, gsum);        // re-zeros gsum
    query_kernel<<<147, 256, 0, stream>>>(Kh, Km, tail, gsum);    // real
    fill_kernel <<<4096, 256, 0, stream>>>(gsum, (v4f*)out, NOUT / 4u);
}

// Round 15
// 60.252 us; speedup vs baseline: 2.4772x; 2.4772x over previous
//
#include <hip/hip_runtime.h>
#include <hip/hip_bf16.h>

// Problem constants: B=64, Cin=3, H=W=64, O=16, k=7, fh=fw=58
#define NBUCK 2048
#define WB 0.005859375f         // bucket width = 12/2048, range [-6, 6)
#define SCALE 170.6666667f      // 1/WB

// output geometry
#define SEG 10092u              // fh*fh*Cin
#define OSEG 161472u            // O*SEG
#define OUT1 10334208u          // B*OSEG
#define NOUT 31002624u          // 3*OUT1

// scratch in the TAIL of d_out (fill overwrites it last). float offsets:
// table slots per channel: [0..16)=F-parts(4 planes each), [16..28)=rows, [28..40)=cols
#define TAIL_BASE (NOUT - 524288u)     // 30,478,336
#define P_TTAB 0u                       // [120][2049] T tables
#define P_STAB 245880u                  // [120] S per table
#define P_PACK 246000u                  // [3][144][64] exact corner pixels

typedef float v4f __attribute__((ext_vector_type(4)));

// ---------------------------------------------------------------------------
// 1) build: 120 independent blocks (c*40 + slot), 1024 threads.
//    Histogram into 2048-bucket LDS hist, then BLOCK-PARALLEL scan:
//    T[b] = T0 + WB*(2*b*C[b] - 2*D[b] - b*N), where C/D are exclusive
//    scans of (c_b, b*c_b) -- ONE hierarchical float2 scan over all 1024
//    threads (R14 lesson: the wave0-serial 64-chunk shuffle chain was ~10us
//    of exposed latency at 1-block/CU occupancy).
// ---------------------------------------------------------------------------
__global__ __launch_bounds__(1024) void build_kernel(
    const float* __restrict__ x, float* __restrict__ tail, float* __restrict__ gsum)
{
    __shared__ float sH[NBUCK];         // 8 KB
    __shared__ float sWc[16], sWd[16];
    const int blk = blockIdx.x;         // == table index, 0..119
    const int c   = blk / 40;
    const int t40 = blk - c * 40;
    const int tid = threadIdx.x;
    sH[tid] = 0.f; sH[tid + 1024] = 0.f;
    if (blk == 0 && tid < 64) gsum[tid] = 0.f;
    __syncthreads();

    if (t40 < 16) {
        // F-part: planes 4g..4g+3 of channel c (+ corner pack)
        const int g = t40;
#pragma unroll
        for (int pb = 0; pb < 4; ++pb) {
            const int batch = g * 4 + pb;
            const int plane = batch * 3 + c;
            float4 val = ((const float4*)x)[plane * 1024 + tid];
            float vv[4] = {val.x, val.y, val.z, val.w};
            const int pix0 = tid * 4;
#pragma unroll
            for (int e = 0; e < 4; ++e) {
                const int idx = pix0 + e;
                const int py = idx >> 6, px = idx & 63;
                const float v = vv[e];
                const int b = min(max((int)fmaf(v, SCALE, 1024.f), 0), NBUCK - 1);
                atomicAdd(&sH[b], 1.f);
                const bool rb = (py < 6) | (py >= 58);
                const bool cb = (px < 6) | (px >= 58);
                if (rb & cb) {
                    const int ri = (py < 6) ? py : py - 52;
                    const int ci = (px < 6) ? px : px - 52;
                    tail[P_PACK + ((unsigned)c * 144 + ri * 12 + ci) * 64u + batch] = v;
                }
            }
        }
    } else if (t40 < 28) {
        // row table ri: row py over all 64 planes of channel c (4096 px)
        const int ri = t40 - 16;
        const int py = (ri < 6) ? ri : ri + 52;
        const int b_ = tid >> 4, q = tid & 15;
        float4 val = ((const float4*)x)[(b_ * 3 + c) * 1024 + py * 16 + q];
        float vv[4] = {val.x, val.y, val.z, val.w};
#pragma unroll
        for (int e = 0; e < 4; ++e) {
            const int b = min(max((int)fmaf(vv[e], SCALE, 1024.f), 0), NBUCK - 1);
            atomicAdd(&sH[b], 1.f);
        }
    } else {
        // col table ci: column px over all rows/planes of channel c (4096 px)
        const int ci = t40 - 28;
        const int px = (ci < 6) ? ci : ci + 52;
        const int b_ = tid >> 4, py0 = (tid & 15) * 4;
        const float* base = x + (b_ * 3 + c) * 4096 + px;
        float vr[4];
#pragma unroll
        for (int e = 0; e < 4; ++e) vr[e] = base[(py0 + e) * 64];
#pragma unroll
        for (int e = 0; e < 4; ++e) {
            const int b = min(max((int)fmaf(vr[e], SCALE, 1024.f), 0), NBUCK - 1);
            atomicAdd(&sH[b], 1.f);
        }
    }
    __syncthreads();

    // ---- block-parallel double-prefix via C/D identity ----
    const int lane = tid & 63;
    const int wid  = tid >> 6;
    const int b0 = 2 * tid, b1 = 2 * tid + 1;
    const float c0 = sH[b0], c1 = sH[b1];
    const float d0 = (float)b0 * c0, d1 = (float)b1 * c1;
    const float cs = c0 + c1, ds = d0 + d1;

    float ic = cs, id = ds;                 // wave inclusive scan (float2)
#pragma unroll
    for (int off = 1; off < 64; off <<= 1) {
        const float tc = __shfl_up(ic, off);
        const float td = __shfl_up(id, off);
        if (lane >= off) { ic += tc; id += td; }
    }
    if (lane == 63) { sWc[wid] = ic; sWd[wid] = id; }
    __syncthreads();

    float baseC = 0.f, baseD = 0.f, Ntot = 0.f, Dtot = 0.f;
#pragma unroll
    for (int w = 0; w < 16; ++w) {
        const float wc = sWc[w], wd = sWd[w];
        Ntot += wc; Dtot += wd;
        if (w < wid) { baseC += wc; baseD += wd; }
    }
    const float Cex = baseC + ic - cs;      // exclusive count prefix at b0
    const float Dex = baseD + id - ds;      // exclusive b*c prefix at b0
    const float T0 = WB * (Dtot + 0.5f * Ntot);

    float* T = tail + P_TTAB + (unsigned)blk * 2049u;
    // T[b] = T0 + WB*(2*b*C[b] - 2*D[b] - b*N)
    T[b0] = T0 + WB * (2.f * (float)b0 * Cex - 2.f * Dex - (float)b0 * Ntot);
    const float C1 = Cex + c0, D1 = Dex + d0;
    T[b1] = T0 + WB * (2.f * (float)b1 * C1 - 2.f * D1 - (float)b1 * Ntot);
    if (tid == 1023) {
        T[NBUCK] = T0 + WB * ((float)NBUCK * Ntot - 2.f * Dtot);
        tail[P_STAB + blk] = T0 - 6.f * Ntot;   // sum of snapped values
    }
}

// ---------------------------------------------------------------------------
// 2) query: 147 blocks = (c, tap). Corner loop unrolled 16x (keeps LDS loads
//    in flight -- un-unrolled it was ~14us of exposed ds_read latency);
//    the 28 table lerps distributed across the 8 sl-lanes (4 slots each).
// ---------------------------------------------------------------------------
__global__ __launch_bounds__(256) void query_kernel(
    const float* __restrict__ Kh, const float* __restrict__ Km,
    const float* __restrict__ tail, float* __restrict__ gsum)
{
    __shared__ float sC[2304];
    __shared__ float sredA[32][8];
    __shared__ float sredL[32][8];

    const int c  = blockIdx.x / 49;
    const int t  = blockIdx.x - c * 49;
    const int dy = t / 7, dx = t - dy * 7;

#pragma unroll
    for (int ii = 0; ii < 9; ++ii) {
        const int i = ii * 256 + threadIdx.x;
        const int cell = i >> 6, batch = i & 63;
        const int qr = cell / 6, qc = cell - qr * 6;
        const int ri = (qr < dy) ? qr : 6 + qr;
        const int ci = (qc < dx) ? qc : 6 + qc;
        sC[i] = tail[P_PACK + ((unsigned)c * 144 + ri * 12 + ci) * 64u + batch];
    }
    __syncthreads();

    const int q  = threadIdx.x >> 3;    // 0..31 = hm*16+o
    const int sl = threadIdx.x & 7;
    const int hm = q >> 4, o = q & 15;
    const float k = (hm ? Km : Kh)[o * 147 + c * 49 + t];

    float accA = 0.f, accL = 0.f;
#pragma unroll 16
    for (int step = 0; step < 288; ++step) {          // exact corners
        const float v = sC[sl + 8 * step];
        accA += fabsf(k - v);
        accL += k - v;
    }

    // distributed table lerps: sl handles s = sl, sl+8, sl+16, sl+24 (<28)
    {
        const float u = fmaf(k, SCALE, 1024.f);
        const int j = min(max((int)u, 0), NBUCK - 1);
        const float fr = u - (float)j;
        float A = 0.f, Sm = 0.f;
        for (int s = sl; s < 28; s += 8) {
            int slot; float sgn;
            if (s < 16)      { slot = s; sgn = 1.f; }
            else if (s < 22) { const int qq = s - 16; slot = 16 + ((qq < dy) ? qq : 6 + qq); sgn = -1.f; }
            else             { const int qq = s - 22; slot = 28 + ((qq < dx) ? qq : 6 + qq); sgn = -1.f; }
            const float* T = tail + P_TTAB + (unsigned)(c * 40 + slot) * 2049u;
            const float lerp = T[j] + fr * (T[j + 1] - T[j]);
            A  += sgn * lerp;
            Sm += sgn * tail[P_STAB + c * 40 + slot];
        }
        accA += A;
        accL -= Sm;
        if (sl == 0) accL += k * 212992.f;   // (58*58 - 36) * 64, added once
    }
    sredA[q][sl] = accA;
    sredL[q][sl] = accL;
    __syncthreads();
    if (threadIdx.x < 64) {
        const int idx  = threadIdx.x >> 1;
        const int part = threadIdx.x & 1;
        const float (*sr)[8] = part ? sredL : sredA;
        float s = 0.f;
#pragma unroll
        for (int qq = 0; qq < 8; ++qq) s += sr[idx][qq];
        atomicAdd(&gsum[part * 32 + idx], s);
    }
}

// ---------------------------------------------------------------------------
// 3) fill: fold A/L banks -> s_hit/s_miss; broadcast-fill 124 MB (roofline).
// ---------------------------------------------------------------------------
__global__ __launch_bounds__(256) void fill_kernel(
    const float* __restrict__ gsum, v4f* __restrict__ out, unsigned n4)
{
    __shared__ float sv[48];
    if (threadIdx.x < 48) {
        const int o = threadIdx.x & 15, grp = threadIdx.x >> 4;
        const float h = -0.5f * (gsum[32 + o] + gsum[o]);
        const float m =  0.5f * (gsum[16 + o] - gsum[48 + o]);
        sv[threadIdx.x] = (grp == 0) ? (h - m) : ((grp == 1) ? h : m);
    }
    __syncthreads();
    const unsigned stride = gridDim.x * blockDim.x;
    for (unsigned i = blockIdx.x * blockDim.x + threadIdx.x; i < n4; i += stride) {
        const unsigned f = i * 4u;
        const unsigned w   = f / OUT1;
        const unsigned rem = f - w * OUT1;
        const unsigned o   = (rem % OSEG) / SEG;
        const float val = sv[w * 16 + o];
        v4f pk = {val, val, val, val};
        __builtin_nontemporal_store(pk, &out[i]);
    }
}

extern "C" void kernel_launch(void* const* d_in, const int* in_sizes, int n_in,
                              void* d_out, int out_size, void* d_ws, size_t ws_size,
                              hipStream_t stream)
{
    const float* x  = (const float*)d_in[0];
    const float* Kh = (const float*)d_in[1];
    const float* Km = (const float*)d_in[2];
    float* out  = (float*)d_out;
    float* tail = out + TAIL_BASE;
    float* gsum = (float*)d_ws;    // 64 floats: [0..32) A-bank, [32..64) L-bank

    build_kernel<<<120, 1024, 0, stream>>>(x, tail, gsum);
    query_kernel<<<147, 256, 0, stream>>>(Kh, Km, tail, gsum);
    fill_kernel <<<4096, 256, 0, stream>>>(gsum, (v4f*)out, NOUT / 4u);
}